// Round 6
// baseline (23892.262 us; speedup 1.0000x reference)
//
#include <hip/hip_runtime.h>
#include <hip/hip_cooperative_groups.h>
#include <cstdint>
#include <cstddef>

#define DEVFN __device__ __forceinline__

DEVFN float sigmf(float x) { return 1.0f / (1.0f + expf(-x)); }

// =====================================================================
// GEMM v4 (unchanged; verified healthy: VGPR 64, no spill, VALU ~75%).
// C[rowmap(m), n] = act( sum_k A[m,k]*B[n,k] + bias[n] )
// Block 512 thr = 8 waves (4m x 2n), macro-tile 128x128, BK=16.
// RMAP: 0 identity; 1: (m%80)*128+m/80 ; 2: (m&127)*10+(m>>7)
// =====================================================================
template <int ACT, int RMAP>
__global__ __launch_bounds__(512, 4) void gemm_k(
    const float* __restrict__ A, const float* __restrict__ B,
    const float* __restrict__ bias, float* __restrict__ C, int K, int ldc) {
  constexpr int SST = 132;
  __shared__ float As[2][16 * SST];
  __shared__ float Bs[2][16 * SST];
  const int tid = threadIdx.x;
  const int mA = blockIdx.y * 128;
  const int n0 = blockIdx.x * 128;

  const int sm = tid >> 2;  // 0..127 (tile row)
  const int sq = tid & 3;   // k-quad 0..3
  const float* __restrict__ Ap = A + (size_t)(mA + sm) * K + sq * 4;
  const float* __restrict__ Bp = B + (size_t)(n0 + sm) * K + sq * 4;

  const int w = tid >> 6;   // 0..7
  const int lane = tid & 63;
  const int am0 = (w >> 1) * 32 + (lane >> 3) * 4;  // LDS m base (4 rows)
  const int bn0 = (w & 1) * 64 + (lane & 7) * 4;    // LDS n base (8 cols)

  const float4 fz = {0.f, 0.f, 0.f, 0.f};
  float4 c0a = fz, c0b = fz, c1a = fz, c1b = fz, c2a = fz, c2b = fz,
         c3a = fz, c3b = fz;

#define STAGE_WR(AW, BW, ga, gb)          \
  do {                                    \
    const int kq = sq * 4;                \
    (AW)[(kq + 0) * SST + sm] = (ga).x;   \
    (AW)[(kq + 1) * SST + sm] = (ga).y;   \
    (AW)[(kq + 2) * SST + sm] = (ga).z;   \
    (AW)[(kq + 3) * SST + sm] = (ga).w;   \
    (BW)[(kq + 0) * SST + sm] = (gb).x;   \
    (BW)[(kq + 1) * SST + sm] = (gb).y;   \
    (BW)[(kq + 2) * SST + sm] = (gb).z;   \
    (BW)[(kq + 3) * SST + sm] = (gb).w;   \
  } while (0)

#define FMA8(AV, CA, CB)            \
  CA.x = fmaf(AV, b0.x, CA.x);      \
  CA.y = fmaf(AV, b0.y, CA.y);      \
  CA.z = fmaf(AV, b0.z, CA.z);      \
  CA.w = fmaf(AV, b0.w, CA.w);      \
  CB.x = fmaf(AV, b1.x, CB.x);      \
  CB.y = fmaf(AV, b1.y, CB.y);      \
  CB.z = fmaf(AV, b1.z, CB.z);      \
  CB.w = fmaf(AV, b1.w, CB.w);

#define COMPUTE_TILE(Ab, Bb)                                    \
  _Pragma("unroll") for (int k = 0; k < 16; ++k) {              \
    const float4 av = *(const float4*)&(Ab)[k * SST + am0];     \
    const float4 b0 = *(const float4*)&(Bb)[k * SST + bn0];     \
    const float4 b1 = *(const float4*)&(Bb)[k * SST + bn0 + 32];\
    FMA8(av.x, c0a, c0b)                                        \
    FMA8(av.y, c1a, c1b)                                        \
    FMA8(av.z, c2a, c2b)                                        \
    FMA8(av.w, c3a, c3b)                                        \
  }

  {
    const float4 ga = *(const float4*)Ap;
    const float4 gb = *(const float4*)Bp;
    STAGE_WR(As[0], Bs[0], ga, gb);
  }
  __syncthreads();

  const int nt = K >> 4;
  for (int t = 0; t < nt - 1; ++t) {
    const int kc = (t + 1) << 4;
    const float4 ga = *(const float4*)(Ap + kc);
    const float4 gb = *(const float4*)(Bp + kc);
    const float* __restrict__ Ab = As[t & 1];
    const float* __restrict__ Bb = Bs[t & 1];
    COMPUTE_TILE(Ab, Bb)
    STAGE_WR(As[(t & 1) ^ 1], Bs[(t & 1) ^ 1], ga, gb);
    __syncthreads();
  }
  {
    const float* __restrict__ Ab = As[(nt - 1) & 1];
    const float* __restrict__ Bb = Bs[(nt - 1) & 1];
    COMPUTE_TILE(Ab, Bb)
  }
#undef STAGE_WR
#undef FMA8
#undef COMPUTE_TILE

  const float4 bv0 = *(const float4*)&bias[n0 + bn0];
  const float4 bv1 = *(const float4*)&bias[n0 + bn0 + 32];
#define EPI_ROW(IDX, CA, CB)                                         \
  {                                                                  \
    const int m = mA + am0 + (IDX);                                  \
    int cr;                                                          \
    if (RMAP == 0) cr = m;                                           \
    else if (RMAP == 1) cr = (m % 80) * 128 + m / 80;                \
    else cr = (m & 127) * 10 + (m >> 7);                             \
    float* Cp = C + (size_t)cr * ldc + n0 + bn0;                     \
    float4 o0, o1;                                                   \
    float v;                                                         \
    v = CA.x + bv0.x; o0.x = ACT ? fmaxf(v, 0.f) : v;                \
    v = CA.y + bv0.y; o0.y = ACT ? fmaxf(v, 0.f) : v;                \
    v = CA.z + bv0.z; o0.z = ACT ? fmaxf(v, 0.f) : v;                \
    v = CA.w + bv0.w; o0.w = ACT ? fmaxf(v, 0.f) : v;                \
    v = CB.x + bv1.x; o1.x = ACT ? fmaxf(v, 0.f) : v;                \
    v = CB.y + bv1.y; o1.y = ACT ? fmaxf(v, 0.f) : v;                \
    v = CB.z + bv1.z; o1.z = ACT ? fmaxf(v, 0.f) : v;                \
    v = CB.w + bv1.w; o1.w = ACT ? fmaxf(v, 0.f) : v;                \
    *(float4*)&Cp[0] = o0;                                           \
    *(float4*)&Cp[32] = o1;                                          \
  }
  EPI_ROW(0, c0a, c0b)
  EPI_ROW(1, c1a, c1b)
  EPI_ROW(2, c2a, c2b)
  EPI_ROW(3, c3a, c3b)
#undef EPI_ROW
}

// =====================================================================
// GRU step body, shared by the cooperative sequence kernel and the
// per-step fallback kernel. Grid decomposition: (jt 0..15, bt 0..7,
// d 0..D-1), 512 threads. Block owns 32 h-outputs x 16 batch rows.
// LDS: h tile 16x512 (stride 516) + gh[96][17]  -> 39.5 KB total,
// so >=1 block/CU under ANY occupancy accounting (coop-launch safe).
// Per wave: 12 gh rows (rl = w*12+q; g=rl>>5, jh=rl&31).
// Lane: b_loc = lane&15, kh = lane>>4 (k segment of 128).
// =====================================================================
DEVFN void gru_body(float* lds_h, float* gh_lds, int tid, int jt, int bt,
                    int d, int i, int T, const float* hsrc, float* hdst,
                    const float* __restrict__ gi, int gi_ld,
                    const float* __restrict__ whh,
                    const float* __restrict__ bhh, float* __restrict__ y,
                    int y_ld) {
  const int doff = d * 1536;
  const int j0 = jt * 32;
  const int b0 = bt * 16;

  // stage h tile (16 x 512), stride 516; zeros when hsrc == nullptr
  if (hsrc) {
    const float* hp = hsrc + ((size_t)(d * 128 + b0)) * 512;
#pragma unroll
    for (int c = 0; c < 4; ++c) {
      const int i4 = c * 512 + tid;
      const int r = i4 >> 7, k4 = i4 & 127;
      *(float4*)&lds_h[r * 516 + k4 * 4] =
          *(const float4*)&hp[(size_t)r * 512 + k4 * 4];
    }
  } else {
    const float4 z4 = {0.f, 0.f, 0.f, 0.f};
#pragma unroll
    for (int c = 0; c < 4; ++c) {
      const int i4 = c * 512 + tid;
      const int r = i4 >> 7, k4 = i4 & 127;
      *(float4*)&lds_h[r * 516 + k4 * 4] = z4;
    }
  }
  __syncthreads();

  const int w = tid >> 6;
  const int lane = tid & 63;
  const int b_loc = lane & 15;
  const int kh = lane >> 4;
  const int kbase = kh * 128;

  const float* wr[12];
#pragma unroll
  for (int q = 0; q < 12; ++q) {
    const int rl = w * 12 + q;
    const int g = rl >> 5, jh = rl & 31;
    wr[q] = whh + ((size_t)(doff + g * 512 + j0 + jh)) * 512 + kbase;
  }
  float acc[12];
#pragma unroll
  for (int q = 0; q < 12; ++q) acc[q] = 0.f;
  const float* hrow = &lds_h[b_loc * 516 + kbase];
  for (int k8 = 0; k8 < 128; k8 += 8) {
    const float4 a0 = *(const float4*)&hrow[k8];
    const float4 a1 = *(const float4*)&hrow[k8 + 4];
#pragma unroll
    for (int q = 0; q < 12; ++q) {
      const float* r_ = wr[q] + k8;
      acc[q] += r_[0] * a0.x + r_[1] * a0.y + r_[2] * a0.z + r_[3] * a0.w +
                r_[4] * a1.x + r_[5] * a1.y + r_[6] * a1.z + r_[7] * a1.w;
    }
  }
#pragma unroll
  for (int q = 0; q < 12; ++q) {
    acc[q] += __shfl_xor(acc[q], 16);
    acc[q] += __shfl_xor(acc[q], 32);
  }
  if (kh == 0) {
#pragma unroll
    for (int q = 0; q < 12; ++q) gh_lds[(w * 12 + q) * 17 + b_loc] = acc[q];
  }
  __syncthreads();

  // gate phase: jh2 minor -> coalesced h/y writes
  const int jh2 = tid & 31;
  const int b2 = tid >> 5;  // 0..15
  const int jg = j0 + jh2;
  const int bg = b0 + b2;
  const int t_d = (d == 0) ? i : (T - 1 - i);
  const float ghr = gh_lds[(jh2) * 17 + b2];
  const float ghz = gh_lds[(32 + jh2) * 17 + b2];
  const float ghn = gh_lds[(64 + jh2) * 17 + b2];
  const float* gir = gi + (size_t)(t_d * 128 + bg) * gi_ld + doff;
  const float g_r = gir[jg];
  const float g_z = gir[512 + jg];
  const float g_n = gir[1024 + jg];
  const float r = sigmf(g_r + ghr + bhh[doff + jg]);
  const float z = sigmf(g_z + ghz + bhh[doff + 512 + jg]);
  const float n = tanhf(g_n + r * (ghn + bhh[doff + 1024 + jg]));
  const float hold = lds_h[b2 * 516 + jg];
  const float hnew = (1.f - z) * n + z * hold;
  hdst[((size_t)(d * 128 + bg)) * 512 + jg] = hnew;
  y[((size_t)(t_d * 128 + bg)) * y_ld + d * 512 + jg] = hnew;
}

// Cooperative sequence kernel: all T steps in one launch.
__global__ __launch_bounds__(512, 1) void gru_seq_k(
    const float* h_init, float* hb0, float* hb1, const float* __restrict__ gi,
    int gi_ld, const float* __restrict__ whh, const float* __restrict__ bhh,
    float* __restrict__ y, int y_ld, int T) {
  cooperative_groups::grid_group grid = cooperative_groups::this_grid();
  __shared__ float lds_h[16 * 516];
  __shared__ float gh_lds[96 * 17];
  const int tid = threadIdx.x;
  const int jt = blockIdx.x, bt = blockIdx.y, d = blockIdx.z;
  for (int i = 0; i < T; ++i) {
    const float* hsrc = (i == 0) ? h_init : ((i & 1) ? hb1 : hb0);
    float* hdst = (i & 1) ? hb0 : hb1;
    gru_body(lds_h, gh_lds, tid, jt, bt, d, i, T, hsrc, hdst, gi, gi_ld, whh,
             bhh, y, y_ld);
    if (i + 1 < T) {
      __threadfence();  // release: L2 writeback (cross-XCD visibility)
      grid.sync();
      __threadfence();  // acquire: L1/L2 invalidate before next-step reads
    }
  }
}

// Per-step fallback kernel (identical math/thread mapping).
__global__ __launch_bounds__(512, 1) void gru_step2_k(
    const float* h_prev, float* h_next, const float* __restrict__ gi,
    int gi_ld, const float* __restrict__ whh, const float* __restrict__ bhh,
    float* __restrict__ y, int y_ld, int i, int T) {
  __shared__ float lds_h[16 * 516];
  __shared__ float gh_lds[96 * 17];
  gru_body(lds_h, gh_lds, threadIdx.x, blockIdx.x, blockIdx.y, blockIdx.z, i,
           T, h_prev, h_next, gi, gi_ld, whh, bhh, y, y_ld);
}

static void run_gru(const float* h_init, float* hb0, float* hb1,
                    const float* gi, int gi_ld, const float* whh,
                    const float* bhh, float* y, int y_ld, int T, int D,
                    hipStream_t stream) {
  void* args[] = {(void*)&h_init, (void*)&hb0, (void*)&hb1, (void*)&gi,
                  (void*)&gi_ld,  (void*)&whh, (void*)&bhh, (void*)&y,
                  (void*)&y_ld,   (void*)&T};
  hipError_t e = hipLaunchCooperativeKernel((void*)gru_seq_k, dim3(16, 8, D),
                                            dim3(512, 1, 1), args, 0, stream);
  if (e != hipSuccess) {
    // deterministic fallback: same body, one launch per step
    for (int i = 0; i < T; ++i) {
      const float* hs = (i == 0) ? h_init : ((i & 1) ? hb1 : hb0);
      float* hd = (i & 1) ? hb0 : hb1;
      gru_step2_k<<<dim3(16, 8, D), dim3(512, 1, 1), 0, stream>>>(
          hs, hd, gi, gi_ld, whh, bhh, y, y_ld, i, T);
    }
  }
}

// =====================================================================
// encode_out[t,b,h] = y1[t,b,h] + y1[t,b,512+h]   (float4 granularity)
// =====================================================================
__global__ void fold_k(const float* __restrict__ y1, float* __restrict__ eo) {
  const size_t i = (size_t)blockIdx.x * 256 + threadIdx.x; // float4 index
  const size_t r = i >> 7;
  const int k4 = (int)(i & 127);
  const float* s = y1 + r * 1024 + k4 * 4;
  const float4 a = *(const float4*)s;
  const float4 c = *(const float4*)(s + 512);
  float4 o;
  o.x = a.x + c.x; o.y = a.y + c.y; o.z = a.z + c.z; o.w = a.w + c.w;
  *(float4*)&eo[r * 512 + k4 * 4] = o;
}

// emb_g[l*128+b, :] = embed[target[b,l], :]
__global__ void gather_k(const float* __restrict__ embed,
                         const int* __restrict__ target,
                         float* __restrict__ out) {
  const int rowid = blockIdx.x; // l*128+b
  const int l = rowid >> 7, b = rowid & 127;
  const int wd = target[b * 10 + l];
  const float4* src = (const float4*)(embed + (size_t)wd * 512);
  float4* dst = (float4*)(out + (size_t)rowid * 512);
  dst[threadIdx.x] = src[threadIdx.x];
}

// =====================================================================
// Attention per (l,b): scores over T=80, softmax, ctx; writes Z row
// [ctx(512) | hn(512)].  enc: (T,B,512) rows t*128+b. hn: (L*B,512).
// =====================================================================
__global__ __launch_bounds__(256) void attn_k(const float* __restrict__ enc,
                                              const float* __restrict__ hn_all,
                                              float* __restrict__ Z) {
  __shared__ float hs[512];
  __shared__ float sc[80];
  __shared__ float att[80];
  const int l = blockIdx.x >> 7;
  const int b = blockIdx.x & 127;
  const int tid = threadIdx.x;
  const size_t hrow = (size_t)(l * 128 + b) * 512;
  if (tid < 128)
    *(float4*)&hs[tid * 4] = *(const float4*)&hn_all[hrow + tid * 4];
  __syncthreads();
  const int w = tid >> 6, lane = tid & 63;
  for (int t = w; t < 80; t += 4) {
    const float* e = enc + ((size_t)(t * 128 + b)) * 512 + lane * 8;
    const float4 e0 = *(const float4*)e;
    const float4 e1 = *(const float4*)(e + 4);
    const float* h8 = &hs[lane * 8];
    float p = e0.x * h8[0] + e0.y * h8[1] + e0.z * h8[2] + e0.w * h8[3] +
              e1.x * h8[4] + e1.y * h8[5] + e1.z * h8[6] + e1.w * h8[7];
#pragma unroll
    for (int off = 1; off < 64; off <<= 1) p += __shfl_xor(p, off);
    if (lane == 0) sc[t] = p;
  }
  __syncthreads();
  if (w == 0) {
    const float v0 = sc[lane];
    const float v1 = (lane < 16) ? sc[64 + lane] : -3.4e38f;
    float m = fmaxf(v0, v1);
#pragma unroll
    for (int off = 1; off < 64; off <<= 1) m = fmaxf(m, __shfl_xor(m, off));
    const float e0 = expf(v0 - m);
    const float e1 = (lane < 16) ? expf(v1 - m) : 0.f;
    float s = e0 + e1;
#pragma unroll
    for (int off = 1; off < 64; off <<= 1) s += __shfl_xor(s, off);
    att[lane] = e0 / s;
    if (lane < 16) att[64 + lane] = e1 / s;
  }
  __syncthreads();
  float c0 = 0.f, c1 = 0.f;
  for (int t = 0; t < 80; ++t) {
    const float* e = enc + ((size_t)(t * 128 + b)) * 512;
    const float a = att[t];
    c0 += a * e[tid];
    c1 += a * e[tid + 256];
  }
  const size_t zr = (size_t)(l * 128 + b) * 1024;
  Z[zr + tid] = c0;
  Z[zr + 256 + tid] = c1;
  Z[zr + 512 + tid] = hs[tid];
  Z[zr + 768 + tid] = hs[256 + tid];
}

// =====================================================================
// Per row (b*10+l) of d_out: argmax (first-index ties) + logsumexp,
// in-place log_softmax, write pre_sent[l*128+b] as float.
// =====================================================================
__global__ __launch_bounds__(256) void lsm_k(float* __restrict__ out) {
  const int row = blockIdx.x; // b*10 + l
  float* p = out + (size_t)row * 32000;
  const int tid = threadIdx.x;
  float bv = -3.4e38f;
  int bi = 0;
  for (int c = 0; c < 125; ++c) {
    const int idx = c * 256 + tid;
    const float v = p[idx];
    if (v > bv || (v == bv && idx < bi)) { bv = v; bi = idx; }
  }
#pragma unroll
  for (int off = 1; off < 64; off <<= 1) {
    const float ov = __shfl_xor(bv, off);
    const int oi = __shfl_xor(bi, off);
    if (ov > bv || (ov == bv && oi < bi)) { bv = ov; bi = oi; }
  }
  __shared__ float wv[4];
  __shared__ int wi[4];
  __shared__ float wsm[4];
  const int w = tid >> 6, lane = tid & 63;
  if (lane == 0) { wv[w] = bv; wi[w] = bi; }
  __syncthreads();
  float m = wv[0];
  int mi = wi[0];
#pragma unroll
  for (int q = 1; q < 4; ++q) {
    if (wv[q] > m || (wv[q] == m && wi[q] < mi)) { m = wv[q]; mi = wi[q]; }
  }
  float s = 0.f;
  for (int c = 0; c < 125; ++c) s += expf(p[c * 256 + tid] - m);
#pragma unroll
  for (int off = 1; off < 64; off <<= 1) s += __shfl_xor(s, off);
  if (lane == 0) wsm[w] = s;
  __syncthreads();
  const float lse = m + logf(wsm[0] + wsm[1] + wsm[2] + wsm[3]);
  for (int c = 0; c < 125; ++c) {
    const int idx = c * 256 + tid;
    p[idx] = p[idx] - lse;
  }
  if (tid == 0) out[40960000 + (row % 10) * 128 + (row / 10)] = (float)mi;
}

// =====================================================================
extern "C" void kernel_launch(void* const* d_in, const int* in_sizes, int n_in,
                              void* d_out, int out_size, void* d_ws,
                              size_t ws_size, hipStream_t stream) {
  (void)in_sizes; (void)n_in; (void)out_size; (void)ws_size;
  const float* data = (const float*)d_in[0];
  const int* target = (const int*)d_in[1];
  const float* enc_lin_w = (const float*)d_in[2];
  const float* enc_lin_b = (const float*)d_in[3];
  const float* enc_wih0 = (const float*)d_in[4];
  const float* enc_whh0 = (const float*)d_in[5];
  const float* enc_bih0 = (const float*)d_in[6];
  const float* enc_bhh0 = (const float*)d_in[7];
  const float* enc_wih1 = (const float*)d_in[8];
  const float* enc_whh1 = (const float*)d_in[9];
  const float* enc_bih1 = (const float*)d_in[10];
  const float* enc_bhh1 = (const float*)d_in[11];
  const float* dec_wih = (const float*)d_in[12];
  const float* dec_whh = (const float*)d_in[13];
  const float* dec_bih = (const float*)d_in[14];
  const float* dec_bhh = (const float*)d_in[15];
  const float* out_w = (const float*)d_in[16];
  const float* out_b = (const float*)d_in[17];
  const float* embed = (const float*)d_in[18];
  float* outp = (float*)d_out;

  float* ws = (float*)d_ws;
  size_t off = 0;
  float* buf_gi = ws + off;  off += 31457280;  // (10240, 3072) gi0 then gi1
  float* buf_x = ws + off;   off += 5242880;   // x (T,B,512); later enc_out
  float* buf_y0 = ws + off;  off += 10485760;  // (T,B,1024)
  float* buf_y1 = ws + off;  off += 10485760;  // (T,B,1024)
  float* h_pp0 = ws + off;   off += 131072;    // (2,128,512)
  float* h_pp1 = ws + off;   off += 131072;
  float* dec_pp0 = ws + off; off += 65536;     // (128,512)
  float* dec_pp1 = ws + off; off += 65536;
  float* emb_g = ws + off;   off += 655360;    // (1280,512)
  float* gi_dec = ws + off;  off += 1966080;   // (1280,1536)
  float* hn_all = ws + off;  off += 655360;    // (1280,512)
  float* Zb = ws + off;      off += 1310720;   // (1280,1024)

  // ---- Encoder linear + ReLU: x(t*128+b, 512) ----
  gemm_k<1, 1><<<dim3(4, 80), 512, 0, stream>>>(data, enc_lin_w, enc_lin_b,
                                                buf_x, 4096, 512);
  // ---- gi0 = x @ wih0^T (+bih0), both dirs stacked in 3072 cols ----
  gemm_k<0, 0><<<dim3(24, 80), 512, 0, stream>>>(buf_x, enc_wih0, enc_bih0,
                                                 buf_gi, 512, 3072);
  // ---- layer-0 recurrence (h_init = nullptr -> zeros) ----
  run_gru(nullptr, h_pp0, h_pp1, buf_gi, 3072, enc_whh0, enc_bhh0, buf_y0,
          1024, 80, 2, stream);
  // ---- gi1 = y0 @ wih1^T (+bih1) ----
  gemm_k<0, 0><<<dim3(24, 80), 512, 0, stream>>>(buf_y0, enc_wih1, enc_bih1,
                                                 buf_gi, 1024, 3072);
  // ---- layer-1 recurrence ----
  run_gru(nullptr, h_pp0, h_pp1, buf_gi, 3072, enc_whh1, enc_bhh1, buf_y1,
          1024, 80, 2, stream);
  // final hidden (both dirs) in h_pp0 (T=80 even); decode_hid = d=1 slice.
  // ---- encode_out = y1[:, :512] + y1[:, 512:]  (into buf_x) ----
  fold_k<<<5120, 256, 0, stream>>>(buf_y1, buf_x);
  // ---- decoder input projections ----
  gather_k<<<1280, 128, 0, stream>>>(embed, target, emb_g);
  gemm_k<0, 0><<<dim3(12, 10), 512, 0, stream>>>(emb_g, dec_wih, dec_bih,
                                                 gi_dec, 512, 1536);
  // ---- decoder hidden chain (teacher forcing) ----
  const float* dec_h0 = h_pp0 + 128 * 512;  // layer-1 backward final hidden
  run_gru(dec_h0, dec_pp0, dec_pp1, gi_dec, 1536, dec_whh, dec_bhh, hn_all,
          512, 10, 1, stream);
  // ---- attention + Z = [ctx | hn] ----
  attn_k<<<1280, 256, 0, stream>>>(buf_x, hn_all, Zb);
  // ---- logits GEMM straight into d_out rows (b*10+l) ----
  gemm_k<0, 2><<<dim3(250, 10), 512, 0, stream>>>(Zb, out_w, out_b, outp, 1024,
                                                  32000);
  // ---- log_softmax in place + argmax -> pre_sent ----
  lsm_k<<<1280, 256, 0, stream>>>(outp);
}

// Round 7
// 11025.186 us; speedup vs baseline: 2.1671x; 2.1671x over previous
//
#include <hip/hip_runtime.h>
#include <hip/hip_cooperative_groups.h>
#include <cstdint>
#include <cstddef>

#define DEVFN __device__ __forceinline__

DEVFN float sigmf(float x) { return 1.0f / (1.0f + expf(-x)); }

// =====================================================================
// GEMM v4 (unchanged; verified healthy: VGPR 64, no spill, VALU ~75%).
// C[rowmap(m), n] = act( sum_k A[m,k]*B[n,k] + bias[n] )
// Block 512 thr = 8 waves (4m x 2n), macro-tile 128x128, BK=16.
// RMAP: 0 identity; 1: (m%80)*128+m/80 ; 2: (m&127)*10+(m>>7)
// =====================================================================
template <int ACT, int RMAP>
__global__ __launch_bounds__(512, 4) void gemm_k(
    const float* __restrict__ A, const float* __restrict__ B,
    const float* __restrict__ bias, float* __restrict__ C, int K, int ldc) {
  constexpr int SST = 132;
  __shared__ float As[2][16 * SST];
  __shared__ float Bs[2][16 * SST];
  const int tid = threadIdx.x;
  const int mA = blockIdx.y * 128;
  const int n0 = blockIdx.x * 128;

  const int sm = tid >> 2;  // 0..127 (tile row)
  const int sq = tid & 3;   // k-quad 0..3
  const float* __restrict__ Ap = A + (size_t)(mA + sm) * K + sq * 4;
  const float* __restrict__ Bp = B + (size_t)(n0 + sm) * K + sq * 4;

  const int w = tid >> 6;   // 0..7
  const int lane = tid & 63;
  const int am0 = (w >> 1) * 32 + (lane >> 3) * 4;  // LDS m base (4 rows)
  const int bn0 = (w & 1) * 64 + (lane & 7) * 4;    // LDS n base (8 cols)

  const float4 fz = {0.f, 0.f, 0.f, 0.f};
  float4 c0a = fz, c0b = fz, c1a = fz, c1b = fz, c2a = fz, c2b = fz,
         c3a = fz, c3b = fz;

#define STAGE_WR(AW, BW, ga, gb)          \
  do {                                    \
    const int kq = sq * 4;                \
    (AW)[(kq + 0) * SST + sm] = (ga).x;   \
    (AW)[(kq + 1) * SST + sm] = (ga).y;   \
    (AW)[(kq + 2) * SST + sm] = (ga).z;   \
    (AW)[(kq + 3) * SST + sm] = (ga).w;   \
    (BW)[(kq + 0) * SST + sm] = (gb).x;   \
    (BW)[(kq + 1) * SST + sm] = (gb).y;   \
    (BW)[(kq + 2) * SST + sm] = (gb).z;   \
    (BW)[(kq + 3) * SST + sm] = (gb).w;   \
  } while (0)

#define FMA8(AV, CA, CB)            \
  CA.x = fmaf(AV, b0.x, CA.x);      \
  CA.y = fmaf(AV, b0.y, CA.y);      \
  CA.z = fmaf(AV, b0.z, CA.z);      \
  CA.w = fmaf(AV, b0.w, CA.w);      \
  CB.x = fmaf(AV, b1.x, CB.x);      \
  CB.y = fmaf(AV, b1.y, CB.y);      \
  CB.z = fmaf(AV, b1.z, CB.z);      \
  CB.w = fmaf(AV, b1.w, CB.w);

#define COMPUTE_TILE(Ab, Bb)                                    \
  _Pragma("unroll") for (int k = 0; k < 16; ++k) {              \
    const float4 av = *(const float4*)&(Ab)[k * SST + am0];     \
    const float4 b0 = *(const float4*)&(Bb)[k * SST + bn0];     \
    const float4 b1 = *(const float4*)&(Bb)[k * SST + bn0 + 32];\
    FMA8(av.x, c0a, c0b)                                        \
    FMA8(av.y, c1a, c1b)                                        \
    FMA8(av.z, c2a, c2b)                                        \
    FMA8(av.w, c3a, c3b)                                        \
  }

  {
    const float4 ga = *(const float4*)Ap;
    const float4 gb = *(const float4*)Bp;
    STAGE_WR(As[0], Bs[0], ga, gb);
  }
  __syncthreads();

  const int nt = K >> 4;
  for (int t = 0; t < nt - 1; ++t) {
    const int kc = (t + 1) << 4;
    const float4 ga = *(const float4*)(Ap + kc);
    const float4 gb = *(const float4*)(Bp + kc);
    const float* __restrict__ Ab = As[t & 1];
    const float* __restrict__ Bb = Bs[t & 1];
    COMPUTE_TILE(Ab, Bb)
    STAGE_WR(As[(t & 1) ^ 1], Bs[(t & 1) ^ 1], ga, gb);
    __syncthreads();
  }
  {
    const float* __restrict__ Ab = As[(nt - 1) & 1];
    const float* __restrict__ Bb = Bs[(nt - 1) & 1];
    COMPUTE_TILE(Ab, Bb)
  }
#undef STAGE_WR
#undef FMA8
#undef COMPUTE_TILE

  const float4 bv0 = *(const float4*)&bias[n0 + bn0];
  const float4 bv1 = *(const float4*)&bias[n0 + bn0 + 32];
#define EPI_ROW(IDX, CA, CB)                                         \
  {                                                                  \
    const int m = mA + am0 + (IDX);                                  \
    int cr;                                                          \
    if (RMAP == 0) cr = m;                                           \
    else if (RMAP == 1) cr = (m % 80) * 128 + m / 80;                \
    else cr = (m & 127) * 10 + (m >> 7);                             \
    float* Cp = C + (size_t)cr * ldc + n0 + bn0;                     \
    float4 o0, o1;                                                   \
    float v;                                                         \
    v = CA.x + bv0.x; o0.x = ACT ? fmaxf(v, 0.f) : v;                \
    v = CA.y + bv0.y; o0.y = ACT ? fmaxf(v, 0.f) : v;                \
    v = CA.z + bv0.z; o0.z = ACT ? fmaxf(v, 0.f) : v;                \
    v = CA.w + bv0.w; o0.w = ACT ? fmaxf(v, 0.f) : v;                \
    v = CB.x + bv1.x; o1.x = ACT ? fmaxf(v, 0.f) : v;                \
    v = CB.y + bv1.y; o1.y = ACT ? fmaxf(v, 0.f) : v;                \
    v = CB.z + bv1.z; o1.z = ACT ? fmaxf(v, 0.f) : v;                \
    v = CB.w + bv1.w; o1.w = ACT ? fmaxf(v, 0.f) : v;                \
    *(float4*)&Cp[0] = o0;                                           \
    *(float4*)&Cp[32] = o1;                                          \
  }
  EPI_ROW(0, c0a, c0b)
  EPI_ROW(1, c1a, c1b)
  EPI_ROW(2, c2a, c2b)
  EPI_ROW(3, c3a, c3b)
#undef EPI_ROW
}

// =====================================================================
// GRU step body (same math/mapping as R6, which passed correctness).
// Grid: (jt 0..15, bt 0..7, d 0..D-1), 512 threads.
// Block owns 32 h-outputs x 16 batch rows. LDS 39.5 KB -> coop-safe.
// h ping-pong traffic uses AGENT-scope atomics (device coherence point,
// bypasses the non-coherent per-XCD L2); whh/gi stay normally cached.
// =====================================================================
DEVFN void gru_body(float* lds_h, float* gh_lds, int tid, int jt, int bt,
                    int d, int i, int T, const float* hsrc, float* hdst,
                    const float* __restrict__ gi, int gi_ld,
                    const float* __restrict__ whh,
                    const float* __restrict__ bhh, float* __restrict__ y,
                    int y_ld) {
  const int doff = d * 1536;
  const int j0 = jt * 32;
  const int b0 = bt * 16;

  // stage h tile (16 x 512), stride 516; zeros when hsrc == nullptr
  if (hsrc) {
    const float* hp = hsrc + ((size_t)(d * 128 + b0)) * 512;
#pragma unroll
    for (int c = 0; c < 16; ++c) {
      const int idx = c * 512 + tid;     // 0..8191
      const int r = idx >> 9, k = idx & 511;
      lds_h[r * 516 + k] = __hip_atomic_load(
          &hp[(size_t)r * 512 + k], __ATOMIC_RELAXED, __HIP_MEMORY_SCOPE_AGENT);
    }
  } else {
    const float4 z4 = {0.f, 0.f, 0.f, 0.f};
#pragma unroll
    for (int c = 0; c < 4; ++c) {
      const int i4 = c * 512 + tid;
      const int r = i4 >> 7, k4 = i4 & 127;
      *(float4*)&lds_h[r * 516 + k4 * 4] = z4;
    }
  }
  __syncthreads();

  const int w = tid >> 6;
  const int lane = tid & 63;
  const int b_loc = lane & 15;
  const int kh = lane >> 4;
  const int kbase = kh * 128;

  const float* wr[12];
#pragma unroll
  for (int q = 0; q < 12; ++q) {
    const int rl = w * 12 + q;
    const int g = rl >> 5, jh = rl & 31;
    wr[q] = whh + ((size_t)(doff + g * 512 + j0 + jh)) * 512 + kbase;
  }
  float acc[12];
#pragma unroll
  for (int q = 0; q < 12; ++q) acc[q] = 0.f;
  const float* hrow = &lds_h[b_loc * 516 + kbase];
  for (int k8 = 0; k8 < 128; k8 += 8) {
    const float4 a0 = *(const float4*)&hrow[k8];
    const float4 a1 = *(const float4*)&hrow[k8 + 4];
#pragma unroll
    for (int q = 0; q < 12; ++q) {
      const float* r_ = wr[q] + k8;
      acc[q] += r_[0] * a0.x + r_[1] * a0.y + r_[2] * a0.z + r_[3] * a0.w +
                r_[4] * a1.x + r_[5] * a1.y + r_[6] * a1.z + r_[7] * a1.w;
    }
  }
#pragma unroll
  for (int q = 0; q < 12; ++q) {
    acc[q] += __shfl_xor(acc[q], 16);
    acc[q] += __shfl_xor(acc[q], 32);
  }
  if (kh == 0) {
#pragma unroll
    for (int q = 0; q < 12; ++q) gh_lds[(w * 12 + q) * 17 + b_loc] = acc[q];
  }
  __syncthreads();

  // gate phase: jh2 minor -> coalesced h/y writes
  const int jh2 = tid & 31;
  const int b2 = tid >> 5;  // 0..15
  const int jg = j0 + jh2;
  const int bg = b0 + b2;
  const int t_d = (d == 0) ? i : (T - 1 - i);
  const float ghr = gh_lds[(jh2) * 17 + b2];
  const float ghz = gh_lds[(32 + jh2) * 17 + b2];
  const float ghn = gh_lds[(64 + jh2) * 17 + b2];
  const float* gir = gi + (size_t)(t_d * 128 + bg) * gi_ld + doff;
  const float g_r = gir[jg];
  const float g_z = gir[512 + jg];
  const float g_n = gir[1024 + jg];
  const float r = sigmf(g_r + ghr + bhh[doff + jg]);
  const float z = sigmf(g_z + ghz + bhh[doff + 512 + jg]);
  const float n = tanhf(g_n + r * (ghn + bhh[doff + 1024 + jg]));
  const float hold = lds_h[b2 * 516 + jg];
  const float hnew = (1.f - z) * n + z * hold;
  __hip_atomic_store(&hdst[((size_t)(d * 128 + bg)) * 512 + jg], hnew,
                     __ATOMIC_RELAXED, __HIP_MEMORY_SCOPE_AGENT);
  y[((size_t)(t_d * 128 + bg)) * y_ld + d * 512 + jg] = hnew;
}

// Cooperative sequence kernel: all T steps in one launch. Sync is a
// hand-rolled 16-block barrier per (bt,d) group (the only blocks that
// share h rows): tid0 release-atomicAdd on bar[i*16+grp], acquire-spin
// to 16, s_sleep backoff. bar zeroed by a captured hipMemsetAsync.
__global__ __launch_bounds__(512, 1) void gru_seq_k(
    const float* h_init, float* hb0, float* hb1, const float* __restrict__ gi,
    int gi_ld, const float* __restrict__ whh, const float* __restrict__ bhh,
    float* __restrict__ y, int y_ld, int T, unsigned* bar) {
  __shared__ float lds_h[16 * 516];
  __shared__ float gh_lds[96 * 17];
  const int tid = threadIdx.x;
  const int jt = blockIdx.x, bt = blockIdx.y, d = blockIdx.z;
  const int grp = bt * gridDim.z + d;  // < 16
  for (int i = 0; i < T; ++i) {
    const float* hsrc = (i == 0) ? h_init : ((i & 1) ? hb1 : hb0);
    float* hdst = (i & 1) ? hb0 : hb1;
    gru_body(lds_h, gh_lds, tid, jt, bt, d, i, T, hsrc, hdst, gi, gi_ld, whh,
             bhh, y, y_ld);
    if (i + 1 < T) {
      __syncthreads();  // all lanes' h-stores issued & drained (vmcnt)
      if (tid == 0) {
        unsigned* c = &bar[(unsigned)i * 16 + grp];
        __hip_atomic_fetch_add(c, 1u, __ATOMIC_RELEASE,
                               __HIP_MEMORY_SCOPE_AGENT);
        while (__hip_atomic_load(c, __ATOMIC_ACQUIRE,
                                 __HIP_MEMORY_SCOPE_AGENT) < 16u)
          __builtin_amdgcn_s_sleep(1);
      }
      __syncthreads();
    }
  }
}

// Per-step fallback kernel (identical math/thread mapping).
__global__ __launch_bounds__(512, 1) void gru_step2_k(
    const float* h_prev, float* h_next, const float* __restrict__ gi,
    int gi_ld, const float* __restrict__ whh, const float* __restrict__ bhh,
    float* __restrict__ y, int y_ld, int i, int T) {
  __shared__ float lds_h[16 * 516];
  __shared__ float gh_lds[96 * 17];
  gru_body(lds_h, gh_lds, threadIdx.x, blockIdx.x, blockIdx.y, blockIdx.z, i,
           T, h_prev, h_next, gi, gi_ld, whh, bhh, y, y_ld);
}

static void run_gru(const float* h_init, float* hb0, float* hb1,
                    const float* gi, int gi_ld, const float* whh,
                    const float* bhh, float* y, int y_ld, int T, int D,
                    unsigned* bar, hipStream_t stream) {
  void* args[] = {(void*)&h_init, (void*)&hb0, (void*)&hb1, (void*)&gi,
                  (void*)&gi_ld,  (void*)&whh, (void*)&bhh, (void*)&y,
                  (void*)&y_ld,   (void*)&T,   (void*)&bar};
  hipError_t e = hipLaunchCooperativeKernel((void*)gru_seq_k, dim3(16, 8, D),
                                            dim3(512, 1, 1), args, 0, stream);
  if (e != hipSuccess) {
    // deterministic fallback: same body, one launch per step
    for (int i = 0; i < T; ++i) {
      const float* hs = (i == 0) ? h_init : ((i & 1) ? hb1 : hb0);
      float* hd = (i & 1) ? hb0 : hb1;
      gru_step2_k<<<dim3(16, 8, D), dim3(512, 1, 1), 0, stream>>>(
          hs, hd, gi, gi_ld, whh, bhh, y, y_ld, i, T);
    }
  }
}

// =====================================================================
// encode_out[t,b,h] = y1[t,b,h] + y1[t,b,512+h]   (float4 granularity)
// =====================================================================
__global__ void fold_k(const float* __restrict__ y1, float* __restrict__ eo) {
  const size_t i = (size_t)blockIdx.x * 256 + threadIdx.x; // float4 index
  const size_t r = i >> 7;
  const int k4 = (int)(i & 127);
  const float* s = y1 + r * 1024 + k4 * 4;
  const float4 a = *(const float4*)s;
  const float4 c = *(const float4*)(s + 512);
  float4 o;
  o.x = a.x + c.x; o.y = a.y + c.y; o.z = a.z + c.z; o.w = a.w + c.w;
  *(float4*)&eo[r * 512 + k4 * 4] = o;
}

// emb_g[l*128+b, :] = embed[target[b,l], :]
__global__ void gather_k(const float* __restrict__ embed,
                         const int* __restrict__ target,
                         float* __restrict__ out) {
  const int rowid = blockIdx.x; // l*128+b
  const int l = rowid >> 7, b = rowid & 127;
  const int wd = target[b * 10 + l];
  const float4* src = (const float4*)(embed + (size_t)wd * 512);
  float4* dst = (float4*)(out + (size_t)rowid * 512);
  dst[threadIdx.x] = src[threadIdx.x];
}

// =====================================================================
// Attention per (l,b): scores over T=80, softmax, ctx; writes Z row
// [ctx(512) | hn(512)].  enc: (T,B,512) rows t*128+b. hn: (L*B,512).
// =====================================================================
__global__ __launch_bounds__(256) void attn_k(const float* __restrict__ enc,
                                              const float* __restrict__ hn_all,
                                              float* __restrict__ Z) {
  __shared__ float hs[512];
  __shared__ float sc[80];
  __shared__ float att[80];
  const int l = blockIdx.x >> 7;
  const int b = blockIdx.x & 127;
  const int tid = threadIdx.x;
  const size_t hrow = (size_t)(l * 128 + b) * 512;
  if (tid < 128)
    *(float4*)&hs[tid * 4] = *(const float4*)&hn_all[hrow + tid * 4];
  __syncthreads();
  const int w = tid >> 6, lane = tid & 63;
  for (int t = w; t < 80; t += 4) {
    const float* e = enc + ((size_t)(t * 128 + b)) * 512 + lane * 8;
    const float4 e0 = *(const float4*)e;
    const float4 e1 = *(const float4*)(e + 4);
    const float* h8 = &hs[lane * 8];
    float p = e0.x * h8[0] + e0.y * h8[1] + e0.z * h8[2] + e0.w * h8[3] +
              e1.x * h8[4] + e1.y * h8[5] + e1.z * h8[6] + e1.w * h8[7];
#pragma unroll
    for (int off = 1; off < 64; off <<= 1) p += __shfl_xor(p, off);
    if (lane == 0) sc[t] = p;
  }
  __syncthreads();
  if (w == 0) {
    const float v0 = sc[lane];
    const float v1 = (lane < 16) ? sc[64 + lane] : -3.4e38f;
    float m = fmaxf(v0, v1);
#pragma unroll
    for (int off = 1; off < 64; off <<= 1) m = fmaxf(m, __shfl_xor(m, off));
    const float e0 = expf(v0 - m);
    const float e1 = (lane < 16) ? expf(v1 - m) : 0.f;
    float s = e0 + e1;
#pragma unroll
    for (int off = 1; off < 64; off <<= 1) s += __shfl_xor(s, off);
    att[lane] = e0 / s;
    if (lane < 16) att[64 + lane] = e1 / s;
  }
  __syncthreads();
  float c0 = 0.f, c1 = 0.f;
  for (int t = 0; t < 80; ++t) {
    const float* e = enc + ((size_t)(t * 128 + b)) * 512;
    const float a = att[t];
    c0 += a * e[tid];
    c1 += a * e[tid + 256];
  }
  const size_t zr = (size_t)(l * 128 + b) * 1024;
  Z[zr + tid] = c0;
  Z[zr + 256 + tid] = c1;
  Z[zr + 512 + tid] = hs[tid];
  Z[zr + 768 + tid] = hs[256 + tid];
}

// =====================================================================
// Per row (b*10+l) of d_out: argmax (first-index ties) + logsumexp,
// in-place log_softmax, write pre_sent[l*128+b] as float.
// =====================================================================
__global__ __launch_bounds__(256) void lsm_k(float* __restrict__ out) {
  const int row = blockIdx.x; // b*10 + l
  float* p = out + (size_t)row * 32000;
  const int tid = threadIdx.x;
  float bv = -3.4e38f;
  int bi = 0;
  for (int c = 0; c < 125; ++c) {
    const int idx = c * 256 + tid;
    const float v = p[idx];
    if (v > bv || (v == bv && idx < bi)) { bv = v; bi = idx; }
  }
#pragma unroll
  for (int off = 1; off < 64; off <<= 1) {
    const float ov = __shfl_xor(bv, off);
    const int oi = __shfl_xor(bi, off);
    if (ov > bv || (ov == bv && oi < bi)) { bv = ov; bi = oi; }
  }
  __shared__ float wv[4];
  __shared__ int wi[4];
  __shared__ float wsm[4];
  const int w = tid >> 6, lane = tid & 63;
  if (lane == 0) { wv[w] = bv; wi[w] = bi; }
  __syncthreads();
  float m = wv[0];
  int mi = wi[0];
#pragma unroll
  for (int q = 1; q < 4; ++q) {
    if (wv[q] > m || (wv[q] == m && wi[q] < mi)) { m = wv[q]; mi = wi[q]; }
  }
  float s = 0.f;
  for (int c = 0; c < 125; ++c) s += expf(p[c * 256 + tid] - m);
#pragma unroll
  for (int off = 1; off < 64; off <<= 1) s += __shfl_xor(s, off);
  if (lane == 0) wsm[w] = s;
  __syncthreads();
  const float lse = m + logf(wsm[0] + wsm[1] + wsm[2] + wsm[3]);
  for (int c = 0; c < 125; ++c) {
    const int idx = c * 256 + tid;
    p[idx] = p[idx] - lse;
  }
  if (tid == 0) out[40960000 + (row % 10) * 128 + (row / 10)] = (float)mi;
}

// =====================================================================
extern "C" void kernel_launch(void* const* d_in, const int* in_sizes, int n_in,
                              void* d_out, int out_size, void* d_ws,
                              size_t ws_size, hipStream_t stream) {
  (void)in_sizes; (void)n_in; (void)out_size; (void)ws_size;
  const float* data = (const float*)d_in[0];
  const int* target = (const int*)d_in[1];
  const float* enc_lin_w = (const float*)d_in[2];
  const float* enc_lin_b = (const float*)d_in[3];
  const float* enc_wih0 = (const float*)d_in[4];
  const float* enc_whh0 = (const float*)d_in[5];
  const float* enc_bih0 = (const float*)d_in[6];
  const float* enc_bhh0 = (const float*)d_in[7];
  const float* enc_wih1 = (const float*)d_in[8];
  const float* enc_whh1 = (const float*)d_in[9];
  const float* enc_bih1 = (const float*)d_in[10];
  const float* enc_bhh1 = (const float*)d_in[11];
  const float* dec_wih = (const float*)d_in[12];
  const float* dec_whh = (const float*)d_in[13];
  const float* dec_bih = (const float*)d_in[14];
  const float* dec_bhh = (const float*)d_in[15];
  const float* out_w = (const float*)d_in[16];
  const float* out_b = (const float*)d_in[17];
  const float* embed = (const float*)d_in[18];
  float* outp = (float*)d_out;

  float* ws = (float*)d_ws;
  size_t off = 0;
  float* buf_gi = ws + off;  off += 31457280;  // (10240, 3072) gi0 then gi1
  float* buf_x = ws + off;   off += 5242880;   // x (T,B,512); later enc_out
  float* buf_y0 = ws + off;  off += 10485760;  // (T,B,1024)
  float* buf_y1 = ws + off;  off += 10485760;  // (T,B,1024)
  float* h_pp0 = ws + off;   off += 131072;    // (2,128,512)
  float* h_pp1 = ws + off;   off += 131072;
  float* dec_pp0 = ws + off; off += 65536;     // (128,512)
  float* dec_pp1 = ws + off; off += 65536;
  float* emb_g = ws + off;   off += 655360;    // (1280,512)
  float* gi_dec = ws + off;  off += 1966080;   // (1280,1536)
  float* hn_all = ws + off;  off += 655360;    // (1280,512)
  float* Zb = ws + off;      off += 1310720;   // (1280,1024)
  unsigned* bar = (unsigned*)(ws + off); off += 4096;  // barrier counters

  // zero barrier counters (captured -> re-zeroed on every graph replay)
  hipMemsetAsync(bar, 0, 4096 * sizeof(unsigned), stream);

  // ---- Encoder linear + ReLU: x(t*128+b, 512) ----
  gemm_k<1, 1><<<dim3(4, 80), 512, 0, stream>>>(data, enc_lin_w, enc_lin_b,
                                                buf_x, 4096, 512);
  // ---- gi0 = x @ wih0^T (+bih0), both dirs stacked in 3072 cols ----
  gemm_k<0, 0><<<dim3(24, 80), 512, 0, stream>>>(buf_x, enc_wih0, enc_bih0,
                                                 buf_gi, 512, 3072);
  // ---- layer-0 recurrence (h_init = nullptr -> zeros) ----
  run_gru(nullptr, h_pp0, h_pp1, buf_gi, 3072, enc_whh0, enc_bhh0, buf_y0,
          1024, 80, 2, bar, stream);
  // ---- gi1 = y0 @ wih1^T (+bih1) ----
  gemm_k<0, 0><<<dim3(24, 80), 512, 0, stream>>>(buf_y0, enc_wih1, enc_bih1,
                                                 buf_gi, 1024, 3072);
  // ---- layer-1 recurrence ----
  run_gru(nullptr, h_pp0, h_pp1, buf_gi, 3072, enc_whh1, enc_bhh1, buf_y1,
          1024, 80, 2, bar + 1280, stream);
  // final hidden (both dirs) in h_pp0 (T=80 even); decode_hid = d=1 slice.
  // ---- encode_out = y1[:, :512] + y1[:, 512:]  (into buf_x) ----
  fold_k<<<5120, 256, 0, stream>>>(buf_y1, buf_x);
  // ---- decoder input projections ----
  gather_k<<<1280, 128, 0, stream>>>(embed, target, emb_g);
  gemm_k<0, 0><<<dim3(12, 10), 512, 0, stream>>>(emb_g, dec_wih, dec_bih,
                                                 gi_dec, 512, 1536);
  // ---- decoder hidden chain (teacher forcing) ----
  const float* dec_h0 = h_pp0 + 128 * 512;  // layer-1 backward final hidden
  run_gru(dec_h0, dec_pp0, dec_pp1, gi_dec, 1536, dec_whh, dec_bhh, hn_all,
          512, 10, 1, bar + 2560, stream);
  // ---- attention + Z = [ctx | hn] ----
  attn_k<<<1280, 256, 0, stream>>>(buf_x, hn_all, Zb);
  // ---- logits GEMM straight into d_out rows (b*10+l) ----
  gemm_k<0, 2><<<dim3(250, 10), 512, 0, stream>>>(Zb, out_w, out_b, outp, 1024,
                                                  32000);
  // ---- log_softmax in place + argmax -> pre_sent ----
  lsm_k<<<1280, 256, 0, stream>>>(outp);
}